// Round 2
// baseline (825.404 us; speedup 1.0000x reference)
//
#include <hip/hip_runtime.h>
#include <math.h>

#define N_NODES 50000
#define N_EDGES 800000
#define IN_F    256
#define HD      128   // H*D
#define NH      4
#define DH      32
#define NEG     0.2f

// ---------------- init: zero d_out, emax keys, denom ----------------
__global__ void k_init(float* __restrict__ out, unsigned* __restrict__ emax_u,
                       float* __restrict__ denom) {
    int i = blockIdx.x * blockDim.x + threadIdx.x;
    if (i < N_NODES * HD) out[i] = 0.f;
    if (i < N_NODES * NH) { emax_u[i] = 0u; denom[i] = 0.f; }
}

// ---------------- projection GEMM: fh = feat @ W^T ----------------
// feat [N, 256] row-major, W [128, 256] row-major -> fh [N, 128]
#define BM 64
#define BN 128
#define BK 32
#define ASTR 68    // padded LDS stride (mult of 4 for b128 alignment, breaks bank collisions)
#define BSTR 132

__launch_bounds__(256)
__global__ void k_gemm(const float* __restrict__ feat, const float* __restrict__ W,
                       float* __restrict__ fh) {
    __shared__ float As[BK][ASTR];  // As[k][m]
    __shared__ float Bs[BK][BSTR];  // Bs[k][n]
    const int tid = threadIdx.x;
    const int ty = tid >> 4;        // 0..15 -> row group
    const int tx = tid & 15;        // 0..15 -> col group
    const int row0 = blockIdx.x * BM;

    float acc[4][8];
#pragma unroll
    for (int r = 0; r < 4; ++r)
#pragma unroll
        for (int j = 0; j < 8; ++j) acc[r][j] = 0.f;

    const int lr = tid >> 3;         // 0..31
    const int lk = (tid & 7) << 2;   // 0,4,...,28

    for (int k0 = 0; k0 < IN_F; k0 += BK) {
        // stage A tile (64 rows x 32 k), transposed into As[k][m]
#pragma unroll
        for (int it = 0; it < 2; ++it) {
            int r = lr + it * 32;
            int gr = row0 + r;
            if (gr >= N_NODES) gr = N_NODES - 1;  // clamp; store is guarded
            float4 v = *(const float4*)(&feat[(size_t)gr * IN_F + k0 + lk]);
            As[lk + 0][r] = v.x;
            As[lk + 1][r] = v.y;
            As[lk + 2][r] = v.z;
            As[lk + 3][r] = v.w;
        }
        // stage B tile (128 cols x 32 k), transposed into Bs[k][n]
#pragma unroll
        for (int it = 0; it < 4; ++it) {
            int c = lr + it * 32;
            float4 v = *(const float4*)(&W[(size_t)c * IN_F + k0 + lk]);
            Bs[lk + 0][c] = v.x;
            Bs[lk + 1][c] = v.y;
            Bs[lk + 2][c] = v.z;
            Bs[lk + 3][c] = v.w;
        }
        __syncthreads();

#pragma unroll
        for (int kk = 0; kk < BK; ++kk) {
            float4 a  = *(const float4*)(&As[kk][ty << 2]);
            float4 b0 = *(const float4*)(&Bs[kk][tx << 3]);
            float4 b1 = *(const float4*)(&Bs[kk][(tx << 3) + 4]);
            float av[4] = {a.x, a.y, a.z, a.w};
            float bv[8] = {b0.x, b0.y, b0.z, b0.w, b1.x, b1.y, b1.z, b1.w};
#pragma unroll
            for (int r = 0; r < 4; ++r)
#pragma unroll
                for (int j = 0; j < 8; ++j) acc[r][j] += av[r] * bv[j];
        }
        __syncthreads();
    }

#pragma unroll
    for (int r = 0; r < 4; ++r) {
        int gr = row0 + (ty << 2) + r;
        if (gr < N_NODES) {
            float4 o0 = make_float4(acc[r][0], acc[r][1], acc[r][2], acc[r][3]);
            float4 o1 = make_float4(acc[r][4], acc[r][5], acc[r][6], acc[r][7]);
            *(float4*)(&fh[(size_t)gr * HD + (tx << 3)])     = o0;
            *(float4*)(&fh[(size_t)gr * HD + (tx << 3) + 4]) = o1;
        }
    }
}

// ---------------- per-node attention logits el/er ----------------
// attn_l/attn_r are [H,D] = 128 floats, indexed directly by c
__global__ void k_elr(const float* __restrict__ fh, const float* __restrict__ al,
                      const float* __restrict__ ar, float* __restrict__ el,
                      float* __restrict__ er) {
    const int tid = threadIdx.x;
    const int n = blockIdx.x * 2 + (tid >> 7);
    const int c = tid & 127;
    if (n >= N_NODES) return;
    float v = fh[(size_t)n * HD + c];
    float sl = v * al[c];
    float sr = v * ar[c];
#pragma unroll
    for (int off = 16; off >= 1; off >>= 1) {
        sl += __shfl_xor(sl, off, 32);
        sr += __shfl_xor(sr, off, 32);
    }
    if ((c & 31) == 0) {
        el[n * NH + (c >> 5)] = sl;
        er[n * NH + (c >> 5)] = sr;
    }
}

// ---------------- monotonic float<->uint key for atomicMax ----------------
__device__ __forceinline__ unsigned fkey(float f) {
    unsigned u = __float_as_uint(f);
    return (u & 0x80000000u) ? ~u : (u | 0x80000000u);
}
__device__ __forceinline__ float funkey(unsigned u) {
    return __uint_as_float((u & 0x80000000u) ? (u ^ 0x80000000u) : ~u);
}

__device__ __forceinline__ float lrelu(float x) { return x > 0.f ? x : NEG * x; }

// ---------------- edge pass 1: scores + segment max ----------------
__global__ void k_escore(const int* __restrict__ src, const int* __restrict__ dst,
                         const float* __restrict__ el, const float* __restrict__ er,
                         float* __restrict__ e_ws, unsigned* __restrict__ emax_u) {
    int e = blockIdx.x * blockDim.x + threadIdx.x;
    if (e >= N_EDGES) return;
    int s = src[e], d = dst[e];
    float4 l = ((const float4*)el)[s];
    float4 r = ((const float4*)er)[d];
    float4 v;
    v.x = lrelu(l.x + r.x);
    v.y = lrelu(l.y + r.y);
    v.z = lrelu(l.z + r.z);
    v.w = lrelu(l.w + r.w);
    ((float4*)e_ws)[e] = v;
    atomicMax(&emax_u[d * NH + 0], fkey(v.x));
    atomicMax(&emax_u[d * NH + 1], fkey(v.y));
    atomicMax(&emax_u[d * NH + 2], fkey(v.z));
    atomicMax(&emax_u[d * NH + 3], fkey(v.w));
}

// ---------------- edge pass 2: exp + segment sum (denom) ----------------
__global__ void k_eexp(const int* __restrict__ dst, float* __restrict__ e_ws,
                       const unsigned* __restrict__ emax_u, float* __restrict__ denom) {
    int e = blockIdx.x * blockDim.x + threadIdx.x;
    if (e >= N_EDGES) return;
    int d = dst[e];
    float4 v = ((const float4*)e_ws)[e];
    float4 ee;
    ee.x = expf(v.x - funkey(emax_u[d * NH + 0]));
    ee.y = expf(v.y - funkey(emax_u[d * NH + 1]));
    ee.z = expf(v.z - funkey(emax_u[d * NH + 2]));
    ee.w = expf(v.w - funkey(emax_u[d * NH + 3]));
    ((float4*)e_ws)[e] = ee;
    atomicAdd(&denom[d * NH + 0], ee.x);
    atomicAdd(&denom[d * NH + 1], ee.y);
    atomicAdd(&denom[d * NH + 2], ee.z);
    atomicAdd(&denom[d * NH + 3], ee.w);
}

// ---------------- edge pass 3: weighted message aggregation ----------------
// rst[d] += ee[e] * fh[src]   (division by denom deferred to k_final)
__launch_bounds__(256)
__global__ void k_agg(const int* __restrict__ src, const int* __restrict__ dst,
                      const float* __restrict__ fh, const float* __restrict__ e_ws,
                      float* __restrict__ out) {
    const int tid = threadIdx.x;
    const int e = blockIdx.x * 2 + (tid >> 7);   // E even; grid = E/2
    const int c = tid & 127;
    if (e >= N_EDGES) return;
    int s = src[e], d = dst[e];
    float w = e_ws[(size_t)e * NH + (c >> 5)];
    float val = fh[(size_t)s * HD + c] * w;
    atomicAdd(&out[(size_t)d * HD + c], val);
}

// ---------------- final: divide by denom, add bias ----------------
__global__ void k_final(float* __restrict__ out, const float* __restrict__ denom,
                        const float* __restrict__ bias) {
    int i = blockIdx.x * blockDim.x + threadIdx.x;
    if (i >= N_NODES * HD) return;
    int c = i & 127;
    int n = i >> 7;
    float den = denom[n * NH + (c >> 5)];
    float o = out[i];
    out[i] = (den > 0.f ? o / den : 0.f) + bias[c];
}

extern "C" void kernel_launch(void* const* d_in, const int* in_sizes, int n_in,
                              void* d_out, int out_size, void* d_ws, size_t ws_size,
                              hipStream_t stream) {
    const float* feat   = (const float*)d_in[0];
    const int*   src    = (const int*)d_in[1];
    const int*   dst    = (const int*)d_in[2];
    const float* W      = (const float*)d_in[3];
    const float* attn_l = (const float*)d_in[4];
    const float* attn_r = (const float*)d_in[5];
    const float* bias   = (const float*)d_in[6];
    float* out = (float*)d_out;

    // workspace layout (floats, 256B-aligned regions):
    // fh[N*128] | e_ws[E*4] | emax_u[N*4] | denom[N*4] | el[N*4] | er[N*4]
    char* ws = (char*)d_ws;
    size_t off = 0;
    auto take = [&](size_t bytes) {
        char* p = ws + off;
        off = (off + bytes + 255) & ~(size_t)255;
        return p;
    };
    float*    fh     = (float*)take((size_t)N_NODES * HD * 4);
    float*    e_ws   = (float*)take((size_t)N_EDGES * NH * 4);
    unsigned* emax_u = (unsigned*)take((size_t)N_NODES * NH * 4);
    float*    denom  = (float*)take((size_t)N_NODES * NH * 4);
    float*    el     = (float*)take((size_t)N_NODES * NH * 4);
    float*    er     = (float*)take((size_t)N_NODES * NH * 4);
    (void)ws_size; (void)in_sizes; (void)n_in; (void)out_size;

    // 1. init accumulators
    k_init<<<(N_NODES * HD + 255) / 256, 256, 0, stream>>>(out, emax_u, denom);
    // 2. projection
    k_gemm<<<(N_NODES + BM - 1) / BM, 256, 0, stream>>>(feat, W, fh);
    // 3. node logits
    k_elr<<<(N_NODES + 1) / 2, 256, 0, stream>>>(fh, attn_l, attn_r, el, er);
    // 4. edge scores + segment max
    k_escore<<<(N_EDGES + 255) / 256, 256, 0, stream>>>(src, dst, el, er, e_ws, emax_u);
    // 5. exp + denom
    k_eexp<<<(N_EDGES + 255) / 256, 256, 0, stream>>>(dst, e_ws, emax_u, denom);
    // 6. aggregate (atomic)
    k_agg<<<(N_EDGES + 1) / 2, 256, 0, stream>>>(src, dst, fh, e_ws, out);
    // 7. normalize + bias
    k_final<<<(N_NODES * HD + 255) / 256, 256, 0, stream>>>(out, denom, bias);
}

// Round 4
// 316.741 us; speedup vs baseline: 2.6059x; 2.6059x over previous
//
#include <hip/hip_runtime.h>
#include <math.h>

#define N_NODES 50000
#define N_EDGES 800000
#define IN_F    256
#define HD      128   // H*D
#define NH      4
#define NEG     0.2f

#define SCAN_B  256
#define NB1     ((N_NODES + SCAN_B - 1) / SCAN_B)   // 196

__device__ __forceinline__ float lrelu(float x) { return x > 0.f ? x : NEG * x; }

// ---------------- init: zero deg + cursor ----------------
__global__ void k_init(int* __restrict__ deg, int* __restrict__ cursor) {
    int i = blockIdx.x * blockDim.x + threadIdx.x;
    if (i < N_NODES) { deg[i] = 0; cursor[i] = 0; }
}

// ---------------- projection GEMM: fh = feat @ W^T ----------------
#define BM 64
#define BK 32
#define ASTR 68
#define BSTR 132

__launch_bounds__(256)
__global__ void k_gemm(const float* __restrict__ feat, const float* __restrict__ W,
                       float* __restrict__ fh) {
    __shared__ float As[BK][ASTR];  // As[k][m]
    __shared__ float Bs[BK][BSTR];  // Bs[k][n]
    const int tid = threadIdx.x;
    const int ty = tid >> 4;
    const int tx = tid & 15;
    const int row0 = blockIdx.x * BM;

    float acc[4][8];
#pragma unroll
    for (int r = 0; r < 4; ++r)
#pragma unroll
        for (int j = 0; j < 8; ++j) acc[r][j] = 0.f;

    const int lr = tid >> 3;
    const int lk = (tid & 7) << 2;

    for (int k0 = 0; k0 < IN_F; k0 += BK) {
#pragma unroll
        for (int it = 0; it < 2; ++it) {
            int r = lr + it * 32;
            int gr = row0 + r;
            if (gr >= N_NODES) gr = N_NODES - 1;
            float4 v = *(const float4*)(&feat[(size_t)gr * IN_F + k0 + lk]);
            As[lk + 0][r] = v.x;
            As[lk + 1][r] = v.y;
            As[lk + 2][r] = v.z;
            As[lk + 3][r] = v.w;
        }
#pragma unroll
        for (int it = 0; it < 4; ++it) {
            int c = lr + it * 32;
            float4 v = *(const float4*)(&W[(size_t)c * IN_F + k0 + lk]);
            Bs[lk + 0][c] = v.x;
            Bs[lk + 1][c] = v.y;
            Bs[lk + 2][c] = v.z;
            Bs[lk + 3][c] = v.w;
        }
        __syncthreads();

#pragma unroll
        for (int kk = 0; kk < BK; ++kk) {
            float4 a  = *(const float4*)(&As[kk][ty << 2]);
            float4 b0 = *(const float4*)(&Bs[kk][tx << 3]);
            float4 b1 = *(const float4*)(&Bs[kk][(tx << 3) + 4]);
            float av[4] = {a.x, a.y, a.z, a.w};
            float bv[8] = {b0.x, b0.y, b0.z, b0.w, b1.x, b1.y, b1.z, b1.w};
#pragma unroll
            for (int r = 0; r < 4; ++r)
#pragma unroll
                for (int j = 0; j < 8; ++j) acc[r][j] += av[r] * bv[j];
        }
        __syncthreads();
    }

#pragma unroll
    for (int r = 0; r < 4; ++r) {
        int gr = row0 + (ty << 2) + r;
        if (gr < N_NODES) {
            float4 o0 = make_float4(acc[r][0], acc[r][1], acc[r][2], acc[r][3]);
            float4 o1 = make_float4(acc[r][4], acc[r][5], acc[r][6], acc[r][7]);
            *(float4*)(&fh[(size_t)gr * HD + (tx << 3)])     = o0;
            *(float4*)(&fh[(size_t)gr * HD + (tx << 3) + 4]) = o1;
        }
    }
}

// ---------------- per-node attention logits el/er ----------------
__global__ void k_elr(const float* __restrict__ fh, const float* __restrict__ al,
                      const float* __restrict__ ar, float* __restrict__ el,
                      float* __restrict__ er) {
    const int tid = threadIdx.x;
    const int n = blockIdx.x * 2 + (tid >> 7);
    const int c = tid & 127;
    if (n >= N_NODES) return;
    float v = fh[(size_t)n * HD + c];
    float sl = v * al[c];
    float sr = v * ar[c];
#pragma unroll
    for (int off = 16; off >= 1; off >>= 1) {
        sl += __shfl_xor(sl, off, 32);
        sr += __shfl_xor(sr, off, 32);
    }
    if ((c & 31) == 0) {
        el[n * NH + (c >> 5)] = sl;
        er[n * NH + (c >> 5)] = sr;
    }
}

// ---------------- degree histogram ----------------
__global__ void k_hist(const int* __restrict__ dst, int* __restrict__ deg) {
    int e = blockIdx.x * blockDim.x + threadIdx.x;
    if (e < N_EDGES) atomicAdd(&deg[dst[e]], 1);
}

// ---------------- scan (3-kernel exclusive scan -> row_ptr) ----------------
__global__ void k_scan1(const int* __restrict__ deg, int* __restrict__ row_ptr,
                        int* __restrict__ bsum) {
    __shared__ int sm[SCAN_B];
    const int tid = threadIdx.x;
    const int t = blockIdx.x * SCAN_B + tid;
    int x = (t < N_NODES) ? deg[t] : 0;
    sm[tid] = x;
    __syncthreads();
#pragma unroll
    for (int off = 1; off < SCAN_B; off <<= 1) {
        int v = (tid >= off) ? sm[tid - off] : 0;
        __syncthreads();
        sm[tid] += v;
        __syncthreads();
    }
    if (t < N_NODES) row_ptr[t + 1] = sm[tid];   // inclusive-within-block, fixed in scan3
    if (tid == SCAN_B - 1) bsum[blockIdx.x] = sm[tid];
}

__global__ void k_scan2(const int* __restrict__ bsum, int* __restrict__ boff) {
    __shared__ int sm[SCAN_B];
    const int tid = threadIdx.x;
    int x = (tid < NB1) ? bsum[tid] : 0;
    sm[tid] = x;
    __syncthreads();
#pragma unroll
    for (int off = 1; off < SCAN_B; off <<= 1) {
        int v = (tid >= off) ? sm[tid - off] : 0;
        __syncthreads();
        sm[tid] += v;
        __syncthreads();
    }
    if (tid < NB1) boff[tid] = sm[tid] - x;      // exclusive block offsets
}

__global__ void k_scan3(int* __restrict__ row_ptr, const int* __restrict__ boff) {
    const int t = blockIdx.x * SCAN_B + threadIdx.x;
    if (t == 0) row_ptr[0] = 0;
    if (t < N_NODES) row_ptr[t + 1] += boff[blockIdx.x];
}

// ---------------- scatter: dst-sorted edges + LeakyReLU scores ----------------
__global__ void k_scatter(const int* __restrict__ src, const int* __restrict__ dst,
                          const float4* __restrict__ el4, const float4* __restrict__ er4,
                          const int* __restrict__ row_ptr, int* __restrict__ cursor,
                          float4* __restrict__ sorted_e, int* __restrict__ sorted_src) {
    int e = blockIdx.x * blockDim.x + threadIdx.x;
    if (e >= N_EDGES) return;
    int s = src[e], d = dst[e];
    int slot = row_ptr[d] + atomicAdd(&cursor[d], 1);
    float4 l = el4[s];
    float4 r = er4[d];
    float4 v;
    v.x = lrelu(l.x + r.x);
    v.y = lrelu(l.y + r.y);
    v.z = lrelu(l.z + r.z);
    v.w = lrelu(l.w + r.w);
    sorted_e[slot] = v;
    sorted_src[slot] = s;
}

// ---------------- fused per-node softmax + aggregation + bias ----------------
// one wave per node; 4 waves (4 nodes) per block
#define AGG_WAVES 4
__launch_bounds__(256)
__global__ void k_node(const int* __restrict__ row_ptr, const int* __restrict__ sorted_src,
                       const float4* __restrict__ sorted_e, const float2* __restrict__ fh2,
                       const float2* __restrict__ bias2, float2* __restrict__ out2) {
    __shared__ float lw[AGG_WAVES][64][4];
    __shared__ int   ls[AGG_WAVES][64];
    const int tid = threadIdx.x;
    const int wv = tid >> 6;
    const int lane = tid & 63;
    const int n = blockIdx.x * AGG_WAVES + wv;
    if (n >= N_NODES) return;
    const int start = row_ptr[n];
    const int end   = row_ptr[n + 1];

    // pass 1: per-head max over this node's edges
    float4 m = make_float4(-INFINITY, -INFINITY, -INFINITY, -INFINITY);
    for (int i = start + lane; i < end; i += 64) {
        float4 s = sorted_e[i];
        m.x = fmaxf(m.x, s.x);
        m.y = fmaxf(m.y, s.y);
        m.z = fmaxf(m.z, s.z);
        m.w = fmaxf(m.w, s.w);
    }
#pragma unroll
    for (int off = 32; off >= 1; off >>= 1) {
        m.x = fmaxf(m.x, __shfl_xor(m.x, off));
        m.y = fmaxf(m.y, __shfl_xor(m.y, off));
        m.z = fmaxf(m.z, __shfl_xor(m.z, off));
        m.w = fmaxf(m.w, __shfl_xor(m.w, off));
    }

    // pass 2: sum of exp
    float4 sum = make_float4(0.f, 0.f, 0.f, 0.f);
    for (int i = start + lane; i < end; i += 64) {
        float4 s = sorted_e[i];
        sum.x += expf(s.x - m.x);
        sum.y += expf(s.y - m.y);
        sum.z += expf(s.z - m.z);
        sum.w += expf(s.w - m.w);
    }
#pragma unroll
    for (int off = 32; off >= 1; off >>= 1) {
        sum.x += __shfl_xor(sum.x, off);
        sum.y += __shfl_xor(sum.y, off);
        sum.z += __shfl_xor(sum.z, off);
        sum.w += __shfl_xor(sum.w, off);
    }
    float4 inv;
    inv.x = sum.x > 0.f ? 1.f / sum.x : 0.f;
    inv.y = sum.y > 0.f ? 1.f / sum.y : 0.f;
    inv.z = sum.z > 0.f ? 1.f / sum.z : 0.f;
    inv.w = sum.w > 0.f ? 1.f / sum.w : 0.f;

    // pass 3: aggregate; lane owns channels 2*lane, 2*lane+1 (same head = lane>>4)
    const int h = lane >> 4;
    float2 acc = make_float2(0.f, 0.f);
    for (int chunk = start; chunk < end; chunk += 64) {
        int e = chunk + lane;
        float4 w = make_float4(0.f, 0.f, 0.f, 0.f);
        int sidx = 0;
        if (e < end) {
            float4 s = sorted_e[e];
            w.x = expf(s.x - m.x) * inv.x;
            w.y = expf(s.y - m.y) * inv.y;
            w.z = expf(s.z - m.z) * inv.z;
            w.w = expf(s.w - m.w) * inv.w;
            sidx = sorted_src[e];
        }
        *(float4*)(&lw[wv][lane][0]) = w;
        ls[wv][lane] = sidx;
        // wave-lockstep: same-wave LDS write->read needs no barrier
        int cnt = min(64, end - chunk);
        for (int j = 0; j < cnt; ++j) {
            float wj = lw[wv][j][h];
            float2 v = fh2[(size_t)ls[wv][j] * 64 + lane];
            acc.x += v.x * wj;
            acc.y += v.y * wj;
        }
    }
    float2 b = bias2[lane];
    out2[(size_t)n * 64 + lane] = make_float2(acc.x + b.x, acc.y + b.y);
}

extern "C" void kernel_launch(void* const* d_in, const int* in_sizes, int n_in,
                              void* d_out, int out_size, void* d_ws, size_t ws_size,
                              hipStream_t stream) {
    const float* feat   = (const float*)d_in[0];
    const int*   src    = (const int*)d_in[1];
    const int*   dst    = (const int*)d_in[2];
    const float* W      = (const float*)d_in[3];
    const float* attn_l = (const float*)d_in[4];
    const float* attn_r = (const float*)d_in[5];
    const float* bias   = (const float*)d_in[6];
    float* out = (float*)d_out;

    char* ws = (char*)d_ws;
    size_t off = 0;
    auto take = [&](size_t bytes) {
        char* p = ws + off;
        off = (off + bytes + 255) & ~(size_t)255;
        return p;
    };
    float* fh         = (float*)take((size_t)N_NODES * HD * 4);     // 25.6 MB
    float4* sorted_e  = (float4*)take((size_t)N_EDGES * 16);        // 12.8 MB
    int*   sorted_src = (int*)take((size_t)N_EDGES * 4);            // 3.2 MB
    float* el         = (float*)take((size_t)N_NODES * NH * 4);
    float* er         = (float*)take((size_t)N_NODES * NH * 4);
    int*   row_ptr    = (int*)take((size_t)(N_NODES + 1) * 4);
    int*   deg        = (int*)take((size_t)N_NODES * 4);
    int*   cursor     = (int*)take((size_t)N_NODES * 4);
    int*   bsum       = (int*)take((size_t)NB1 * 4);
    int*   boff       = (int*)take((size_t)NB1 * 4);
    (void)ws_size; (void)in_sizes; (void)n_in; (void)out_size;

    k_init<<<(N_NODES + 255) / 256, 256, 0, stream>>>(deg, cursor);
    k_hist<<<(N_EDGES + 255) / 256, 256, 0, stream>>>(dst, deg);
    k_scan1<<<NB1, SCAN_B, 0, stream>>>(deg, row_ptr, bsum);
    k_scan2<<<1, SCAN_B, 0, stream>>>(bsum, boff);
    k_scan3<<<NB1, SCAN_B, 0, stream>>>(row_ptr, boff);
    k_gemm<<<(N_NODES + BM - 1) / BM, 256, 0, stream>>>(feat, W, fh);
    k_elr<<<(N_NODES + 1) / 2, 256, 0, stream>>>(fh, attn_l, attn_r, el, er);
    k_scatter<<<(N_EDGES + 255) / 256, 256, 0, stream>>>(
        src, dst, (const float4*)el, (const float4*)er, row_ptr, cursor,
        sorted_e, sorted_src);
    k_node<<<(N_NODES + AGG_WAVES - 1) / AGG_WAVES, 256, 0, stream>>>(
        row_ptr, sorted_src, sorted_e, (const float2*)fh,
        (const float2*)bias, (float2*)out);
}

// Round 10
// 276.398 us; speedup vs baseline: 2.9863x; 1.1460x over previous
//
#include <hip/hip_runtime.h>
#include <math.h>

#define N_NODES 50000
#define N_EDGES 800000
#define IN_F    256
#define HD      128   // H*D
#define NH      4
#define NEG     0.2f

#define SCAN_B  256
#define NB1     ((N_NODES + SCAN_B - 1) / SCAN_B)   // 196

typedef __attribute__((ext_vector_type(8))) short short8;   // 8 x bf16 (guide-verified frag type)
typedef __attribute__((ext_vector_type(4))) float f32x4;
typedef __attribute__((ext_vector_type(4))) unsigned int u32x4;

__device__ __forceinline__ float lrelu(float x) { return x > 0.f ? x : NEG * x; }

// ---------------- init: zero deg + cursor ----------------
__global__ void k_init(int* __restrict__ deg, int* __restrict__ cursor) {
    int i = blockIdx.x * blockDim.x + threadIdx.x;
    if (i < N_NODES) { deg[i] = 0; cursor[i] = 0; }
}

// ---------------- degree histogram ----------------
__global__ void k_hist(const int* __restrict__ dst, int* __restrict__ deg) {
    int e = blockIdx.x * blockDim.x + threadIdx.x;
    if (e < N_EDGES) atomicAdd(&deg[dst[e]], 1);
}

// ---------------- scan (3-kernel exclusive scan -> row_ptr) ----------------
__global__ void k_scan1(const int* __restrict__ deg, int* __restrict__ row_ptr,
                        int* __restrict__ bsum) {
    __shared__ int sm[SCAN_B];
    const int tid = threadIdx.x;
    const int t = blockIdx.x * SCAN_B + tid;
    int x = (t < N_NODES) ? deg[t] : 0;
    sm[tid] = x;
    __syncthreads();
#pragma unroll
    for (int off = 1; off < SCAN_B; off <<= 1) {
        int v = (tid >= off) ? sm[tid - off] : 0;
        __syncthreads();
        sm[tid] += v;
        __syncthreads();
    }
    if (t < N_NODES) row_ptr[t + 1] = sm[tid];
    if (tid == SCAN_B - 1) bsum[blockIdx.x] = sm[tid];
}

__global__ void k_scan2(const int* __restrict__ bsum, int* __restrict__ boff) {
    __shared__ int sm[SCAN_B];
    const int tid = threadIdx.x;
    int x = (tid < NB1) ? bsum[tid] : 0;
    sm[tid] = x;
    __syncthreads();
#pragma unroll
    for (int off = 1; off < SCAN_B; off <<= 1) {
        int v = (tid >= off) ? sm[tid - off] : 0;
        __syncthreads();
        sm[tid] += v;
        __syncthreads();
    }
    if (tid < NB1) boff[tid] = sm[tid] - x;
}

__global__ void k_scan3(int* __restrict__ row_ptr, const int* __restrict__ boff) {
    const int t = blockIdx.x * SCAN_B + threadIdx.x;
    if (t == 0) row_ptr[0] = 0;
    if (t < N_NODES) row_ptr[t + 1] += boff[blockIdx.x];
}

// ---------------- scatter: only src ids, dst-sorted (4B/edge) ----------------
__global__ void k_scatter(const int* __restrict__ src, const int* __restrict__ dst,
                          const int* __restrict__ row_ptr, int* __restrict__ cursor,
                          int* __restrict__ sorted_src) {
    int e = blockIdx.x * blockDim.x + threadIdx.x;
    if (e >= N_EDGES) return;
    int d = dst[e];
    int slot = row_ptr[d] + atomicAdd(&cursor[d], 1);
    sorted_src[slot] = src[e];
}

// ---------------- split-bf16 MFMA GEMM: fh = feat @ W^T ----------------
// fp32 -> (hi,lo) bf16 split; D = AhBh + AhBl + AlBh (AlBl dropped, ~2e-4 abs)
#define BM 64
#define KP 40   // padded k-stride in bf16 elems (80B rows -> conflict-light, 16B aligned)

__device__ __forceinline__ void split8(const float* __restrict__ p,
                                       unsigned* __restrict__ hu, unsigned* __restrict__ lu) {
    float v[8];
    *(float4*)(v)     = *(const float4*)(p);
    *(float4*)(v + 4) = *(const float4*)(p + 4);
#pragma unroll
    for (int j = 0; j < 4; ++j) {
        float a = v[2 * j], b = v[2 * j + 1];
        unsigned ha = __float_as_uint(a) >> 16;
        unsigned hb = __float_as_uint(b) >> 16;
        float ra = a - __uint_as_float(ha << 16);
        float rb = b - __uint_as_float(hb << 16);
        unsigned la = __float_as_uint(ra) >> 16;
        unsigned lb = __float_as_uint(rb) >> 16;
        hu[j] = ha | (hb << 16);
        lu[j] = la | (lb << 16);
    }
}

__launch_bounds__(256)
__global__ void k_gemm(const float* __restrict__ feat, const float* __restrict__ W,
                       float* __restrict__ fh) {
    __shared__ unsigned short Ah[BM][KP], Al[BM][KP];
    __shared__ unsigned short Bh[HD][KP], Bl[HD][KP];
    const int tid = threadIdx.x;
    const int w = tid >> 6;        // wave 0..3 -> rows w*16..w*16+15
    const int l = tid & 63;
    const int row0 = blockIdx.x * BM;

    f32x4 acc[8];
#pragma unroll
    for (int f = 0; f < 8; ++f) acc[f] = (f32x4)(0.f);

    // staging assignment: A = 64 rows x 32k (8 floats/thread), B = 128 rows x 32k (16/thread)
    const int ar = tid >> 2;
    const int ak = (tid & 3) << 3;
    const int br = tid >> 1;
    const int bk = (tid & 1) << 4;
    int agr = row0 + ar; if (agr >= N_NODES) agr = N_NODES - 1;  // clamp; stores guarded
    const float* aptr = &feat[(size_t)agr * IN_F + ak];
    const float* bptr = &W[(size_t)br * IN_F + bk];

    const int fr = (w << 4) + (l & 15);   // A frag row within tile
    const int fo = (l >> 4) << 3;         // k-octet offset (8 contiguous bf16)

    for (int k0 = 0; k0 < IN_F; k0 += 32) {
        unsigned hua[4], lua[4], hb0[4], lb0[4], hb1[4], lb1[4];
        split8(aptr + k0, hua, lua);
        split8(bptr + k0, hb0, lb0);
        split8(bptr + k0 + 8, hb1, lb1);
        __syncthreads();   // previous iteration's frag reads done
        *(u32x4*)&Ah[ar][ak]     = (u32x4){hua[0], hua[1], hua[2], hua[3]};
        *(u32x4*)&Al[ar][ak]     = (u32x4){lua[0], lua[1], lua[2], lua[3]};
        *(u32x4*)&Bh[br][bk]     = (u32x4){hb0[0], hb0[1], hb0[2], hb0[3]};
        *(u32x4*)&Bl[br][bk]     = (u32x4){lb0[0], lb0[1], lb0[2], lb0[3]};
        *(u32x4*)&Bh[br][bk + 8] = (u32x4){hb1[0], hb1[1], hb1[2], hb1[3]};
        *(u32x4*)&Bl[br][bk + 8] = (u32x4){lb1[0], lb1[1], lb1[2], lb1[3]};
        __syncthreads();

        short8 a_h = *(short8*)&Ah[fr][fo];
        short8 a_l = *(short8*)&Al[fr][fo];
#pragma unroll
        for (int f = 0; f < 8; ++f) {
            short8 b_h = *(short8*)&Bh[(f << 4) + (l & 15)][fo];
            short8 b_l = *(short8*)&Bl[(f << 4) + (l & 15)][fo];
            acc[f] = __builtin_amdgcn_mfma_f32_16x16x32_bf16(a_h, b_h, acc[f], 0, 0, 0);
            acc[f] = __builtin_amdgcn_mfma_f32_16x16x32_bf16(a_h, b_l, acc[f], 0, 0, 0);
            acc[f] = __builtin_amdgcn_mfma_f32_16x16x32_bf16(a_l, b_h, acc[f], 0, 0, 0);
        }
    }

    // C/D layout (m89-verified): col = lane&15, row = (lane>>4)*4 + reg
    const int rbase = row0 + (w << 4) + ((l >> 4) << 2);
    const int col = l & 15;
#pragma unroll
    for (int f = 0; f < 8; ++f)
#pragma unroll
        for (int r = 0; r < 4; ++r) {
            int gr = rbase + r;
            if (gr < N_NODES)
                fh[(size_t)gr * HD + (f << 4) + col] = acc[f][r];
        }
}

// ---------------- per-node attention logits el/er ----------------
__global__ void k_elr(const float* __restrict__ fh, const float* __restrict__ al,
                      const float* __restrict__ ar, float* __restrict__ el,
                      float* __restrict__ er) {
    const int tid = threadIdx.x;
    const int n = blockIdx.x * 2 + (tid >> 7);
    const int c = tid & 127;
    if (n >= N_NODES) return;
    float v = fh[(size_t)n * HD + c];
    float sl = v * al[c];
    float sr = v * ar[c];
#pragma unroll
    for (int off = 16; off >= 1; off >>= 1) {
        sl += __shfl_xor(sl, off, 32);
        sr += __shfl_xor(sr, off, 32);
    }
    if ((c & 31) == 0) {
        el[n * NH + (c >> 5)] = sl;
        er[n * NH + (c >> 5)] = sr;
    }
}

// ---------------- fused per-node online softmax + aggregation + bias ----------------
// 32-lane group per node (deg avg 16); 8 nodes / 256-thr block; single edge pass
#define NPB 8
__launch_bounds__(256)
__global__ void k_node(const int* __restrict__ row_ptr, const int* __restrict__ sorted_src,
                       const float4* __restrict__ el4, const float4* __restrict__ er4,
                       const float4* __restrict__ fh4, const float4* __restrict__ bias4,
                       float4* __restrict__ out4) {
    __shared__ float lp[NPB][32 * 5];   // stride-5: conflict-free scalar writes
    __shared__ int   lsrc[NPB][32];
    const int tid = threadIdx.x;
    const int g = tid >> 5;
    const int lane = tid & 31;
    const int n = blockIdx.x * NPB + g;
    if (n >= N_NODES) return;
    const int start = row_ptr[n], end = row_ptr[n + 1];
    const int h = lane >> 3;            // head of my 4 channels (lane*4 .. lane*4+3)

    const float4 r4 = er4[n];
    float4 m = make_float4(-INFINITY, -INFINITY, -INFINITY, -INFINITY);
    float4 s = make_float4(0.f, 0.f, 0.f, 0.f);
    float4 acc = make_float4(0.f, 0.f, 0.f, 0.f);

    for (int chunk = start; chunk < end; chunk += 32) {
        const int e = chunk + lane;
        float4 sc = make_float4(-INFINITY, -INFINITY, -INFINITY, -INFINITY);
        int sidx = 0;
        if (e < end) {
            sidx = sorted_src[e];
            float4 l4 = el4[sidx];
            sc.x = lrelu(l4.x + r4.x);
            sc.y = lrelu(l4.y + r4.y);
            sc.z = lrelu(l4.z + r4.z);
            sc.w = lrelu(l4.w + r4.w);
        }
        // chunk max (32-lane reduce)
        float4 cm = sc;
#pragma unroll
        for (int off = 16; off >= 1; off >>= 1) {
            cm.x = fmaxf(cm.x, __shfl_xor(cm.x, off, 32));
            cm.y = fmaxf(cm.y, __shfl_xor(cm.y, off, 32));
            cm.z = fmaxf(cm.z, __shfl_xor(cm.z, off, 32));
            cm.w = fmaxf(cm.w, __shfl_xor(cm.w, off, 32));
        }
        float4 mn;
        mn.x = fmaxf(m.x, cm.x); mn.y = fmaxf(m.y, cm.y);
        mn.z = fmaxf(m.z, cm.z); mn.w = fmaxf(m.w, cm.w);
        float4 scale;
        scale.x = expf(m.x - mn.x); scale.y = expf(m.y - mn.y);
        scale.z = expf(m.z - mn.z); scale.w = expf(m.w - mn.w);
        m = mn;
        float4 p;
        p.x = expf(sc.x - mn.x); p.y = expf(sc.y - mn.y);
        p.z = expf(sc.z - mn.z); p.w = expf(sc.w - mn.w);   // invalid lanes: exp(-inf)=0
        float4 ps = p;
#pragma unroll
        for (int off = 16; off >= 1; off >>= 1) {
            ps.x += __shfl_xor(ps.x, off, 32);
            ps.y += __shfl_xor(ps.y, off, 32);
            ps.z += __shfl_xor(ps.z, off, 32);
            ps.w += __shfl_xor(ps.w, off, 32);
        }
        s.x = s.x * scale.x + ps.x;
        s.y = s.y * scale.y + ps.y;
        s.z = s.z * scale.z + ps.z;
        s.w = s.w * scale.w + ps.w;
        float sh = h == 0 ? scale.x : h == 1 ? scale.y : h == 2 ? scale.z : scale.w;
        acc.x *= sh; acc.y *= sh; acc.z *= sh; acc.w *= sh;

        lp[g][lane * 5 + 0] = p.x;
        lp[g][lane * 5 + 1] = p.y;
        lp[g][lane * 5 + 2] = p.z;
        lp[g][lane * 5 + 3] = p.w;
        lsrc[g][lane] = sidx;
        // same 32-lane group wrote these; wave-lockstep -> no barrier
        const int cnt = min(32, end - chunk);
        for (int j = 0; j < cnt; ++j) {
            float pj = lp[g][j * 5 + h];
            float4 v = fh4[(size_t)lsrc[g][j] * 32 + lane];
            acc.x += v.x * pj; acc.y += v.y * pj;
            acc.z += v.z * pj; acc.w += v.w * pj;
        }
    }
    float den = h == 0 ? s.x : h == 1 ? s.y : h == 2 ? s.z : s.w;
    float inv = den > 0.f ? 1.f / den : 0.f;
    float4 b = bias4[lane];
    float4 o;
    o.x = acc.x * inv + b.x; o.y = acc.y * inv + b.y;
    o.z = acc.z * inv + b.z; o.w = acc.w * inv + b.w;
    out4[(size_t)n * 32 + lane] = o;
}

extern "C" void kernel_launch(void* const* d_in, const int* in_sizes, int n_in,
                              void* d_out, int out_size, void* d_ws, size_t ws_size,
                              hipStream_t stream) {
    const float* feat   = (const float*)d_in[0];
    const int*   src    = (const int*)d_in[1];
    const int*   dst    = (const int*)d_in[2];
    const float* W      = (const float*)d_in[3];
    const float* attn_l = (const float*)d_in[4];
    const float* attn_r = (const float*)d_in[5];
    const float* bias   = (const float*)d_in[6];
    float* out = (float*)d_out;

    char* ws = (char*)d_ws;
    size_t off = 0;
    auto take = [&](size_t bytes) {
        char* p = ws + off;
        off = (off + bytes + 255) & ~(size_t)255;
        return p;
    };
    float* fh         = (float*)take((size_t)N_NODES * HD * 4);   // 25.6 MB
    int*   sorted_src = (int*)take((size_t)N_EDGES * 4);          // 3.2 MB
    float* el         = (float*)take((size_t)N_NODES * NH * 4);
    float* er         = (float*)take((size_t)N_NODES * NH * 4);
    int*   row_ptr    = (int*)take((size_t)(N_NODES + 1) * 4);
    int*   deg        = (int*)take((size_t)N_NODES * 4);
    int*   cursor     = (int*)take((size_t)N_NODES * 4);
    int*   bsum       = (int*)take((size_t)NB1 * 4);
    int*   boff       = (int*)take((size_t)NB1 * 4);
    (void)ws_size; (void)in_sizes; (void)n_in; (void)out_size;

    k_init<<<(N_NODES + 255) / 256, 256, 0, stream>>>(deg, cursor);
    k_hist<<<(N_EDGES + 255) / 256, 256, 0, stream>>>(dst, deg);
    k_scan1<<<NB1, SCAN_B, 0, stream>>>(deg, row_ptr, bsum);
    k_scan2<<<1, SCAN_B, 0, stream>>>(bsum, boff);
    k_scan3<<<NB1, SCAN_B, 0, stream>>>(row_ptr, boff);
    k_scatter<<<(N_EDGES + 255) / 256, 256, 0, stream>>>(src, dst, row_ptr, cursor, sorted_src);
    k_gemm<<<(N_NODES + BM - 1) / BM, 256, 0, stream>>>(feat, W, fh);
    k_elr<<<(N_NODES + 1) / 2, 256, 0, stream>>>(fh, attn_l, attn_r, el, er);
    k_node<<<(N_NODES + NPB - 1) / NPB, 256, 0, stream>>>(
        row_ptr, sorted_src, (const float4*)el, (const float4*)er,
        (const float4*)fh, (const float4*)bias, (float4*)out);
}

// Round 11
// 245.981 us; speedup vs baseline: 3.3556x; 1.1237x over previous
//
#include <hip/hip_runtime.h>
#include <math.h>

#define N_NODES 50000
#define N_EDGES 800000
#define IN_F    256
#define HD      128   // H*D
#define NH      4
#define NEG     0.2f

#define SCAN_B  256
#define NB1     ((N_NODES + SCAN_B - 1) / SCAN_B)   // 196

typedef __attribute__((ext_vector_type(8))) short short8;   // 8 x bf16 (guide-verified frag type)
typedef __attribute__((ext_vector_type(4))) float f32x4;
typedef __attribute__((ext_vector_type(4))) unsigned int u32x4;

__device__ __forceinline__ float lrelu(float x) { return x > 0.f ? x : NEG * x; }

// ---------------- init: zero deg + cursor ----------------
__global__ void k_init(int* __restrict__ deg, int* __restrict__ cursor) {
    int i = blockIdx.x * blockDim.x + threadIdx.x;
    if (i < N_NODES) { deg[i] = 0; cursor[i] = 0; }
}

// ---------------- degree histogram ----------------
__global__ void k_hist(const int* __restrict__ dst, int* __restrict__ deg) {
    int e = blockIdx.x * blockDim.x + threadIdx.x;
    if (e < N_EDGES) atomicAdd(&deg[dst[e]], 1);
}

// ---------------- scan (3-kernel exclusive scan -> row_ptr) ----------------
__global__ void k_scan1(const int* __restrict__ deg, int* __restrict__ row_ptr,
                        int* __restrict__ bsum) {
    __shared__ int sm[SCAN_B];
    const int tid = threadIdx.x;
    const int t = blockIdx.x * SCAN_B + tid;
    int x = (t < N_NODES) ? deg[t] : 0;
    sm[tid] = x;
    __syncthreads();
#pragma unroll
    for (int off = 1; off < SCAN_B; off <<= 1) {
        int v = (tid >= off) ? sm[tid - off] : 0;
        __syncthreads();
        sm[tid] += v;
        __syncthreads();
    }
    if (t < N_NODES) row_ptr[t + 1] = sm[tid];
    if (tid == SCAN_B - 1) bsum[blockIdx.x] = sm[tid];
}

__global__ void k_scan2(const int* __restrict__ bsum, int* __restrict__ boff) {
    __shared__ int sm[SCAN_B];
    const int tid = threadIdx.x;
    int x = (tid < NB1) ? bsum[tid] : 0;
    sm[tid] = x;
    __syncthreads();
#pragma unroll
    for (int off = 1; off < SCAN_B; off <<= 1) {
        int v = (tid >= off) ? sm[tid - off] : 0;
        __syncthreads();
        sm[tid] += v;
        __syncthreads();
    }
    if (tid < NB1) boff[tid] = sm[tid] - x;
}

__global__ void k_scan3(int* __restrict__ row_ptr, const int* __restrict__ boff) {
    const int t = blockIdx.x * SCAN_B + threadIdx.x;
    if (t == 0) row_ptr[0] = 0;
    if (t < N_NODES) row_ptr[t + 1] += boff[blockIdx.x];
}

// ---------------- scatter: only src ids, dst-sorted (4B/edge) ----------------
__global__ void k_scatter(const int* __restrict__ src, const int* __restrict__ dst,
                          const int* __restrict__ row_ptr, int* __restrict__ cursor,
                          int* __restrict__ sorted_src) {
    int e = blockIdx.x * blockDim.x + threadIdx.x;
    if (e >= N_EDGES) return;
    int d = dst[e];
    int slot = row_ptr[d] + atomicAdd(&cursor[d], 1);
    sorted_src[slot] = src[e];
}

// ---------------- split-bf16 MFMA GEMM + fused el/er epilogue ----------------
// fh stored as bf16 [N][128]; el/er computed from fp32 accumulators in-block.
#define BM 64
#define KP 40   // padded k-stride in bf16 elems

__device__ __forceinline__ void split8(const float* __restrict__ p,
                                       unsigned* __restrict__ hu, unsigned* __restrict__ lu) {
    float v[8];
    *(float4*)(v)     = *(const float4*)(p);
    *(float4*)(v + 4) = *(const float4*)(p + 4);
#pragma unroll
    for (int j = 0; j < 4; ++j) {
        float a = v[2 * j], b = v[2 * j + 1];
        unsigned ha = __float_as_uint(a) >> 16;
        unsigned hb = __float_as_uint(b) >> 16;
        float ra = a - __uint_as_float(ha << 16);
        float rb = b - __uint_as_float(hb << 16);
        unsigned la = __float_as_uint(ra) >> 16;
        unsigned lb = __float_as_uint(rb) >> 16;
        hu[j] = ha | (hb << 16);
        lu[j] = la | (lb << 16);
    }
}

__launch_bounds__(256)
__global__ void k_gemm(const float* __restrict__ feat, const float* __restrict__ W,
                       const float* __restrict__ gal, const float* __restrict__ gar,
                       unsigned short* __restrict__ fhb,
                       float* __restrict__ el, float* __restrict__ er) {
    __shared__ unsigned short Ah[BM][KP], Al[BM][KP];
    __shared__ unsigned short Bh[HD][KP], Bl[HD][KP];
    const int tid = threadIdx.x;
    const int w = tid >> 6;
    const int l = tid & 63;
    const int row0 = blockIdx.x * BM;

    f32x4 acc[8];
#pragma unroll
    for (int f = 0; f < 8; ++f) acc[f] = (f32x4)(0.f);

    const int ar = tid >> 2;
    const int ak = (tid & 3) << 3;
    const int br = tid >> 1;
    const int bk = (tid & 1) << 4;
    int agr = row0 + ar; if (agr >= N_NODES) agr = N_NODES - 1;  // clamp; stores guarded
    const float* aptr = &feat[(size_t)agr * IN_F + ak];
    const float* bptr = &W[(size_t)br * IN_F + bk];

    const int fr = (w << 4) + (l & 15);
    const int fo = (l >> 4) << 3;

    for (int k0 = 0; k0 < IN_F; k0 += 32) {
        unsigned hua[4], lua[4], hb0[4], lb0[4], hb1[4], lb1[4];
        split8(aptr + k0, hua, lua);
        split8(bptr + k0, hb0, lb0);
        split8(bptr + k0 + 8, hb1, lb1);
        __syncthreads();
        *(u32x4*)&Ah[ar][ak]     = (u32x4){hua[0], hua[1], hua[2], hua[3]};
        *(u32x4*)&Al[ar][ak]     = (u32x4){lua[0], lua[1], lua[2], lua[3]};
        *(u32x4*)&Bh[br][bk]     = (u32x4){hb0[0], hb0[1], hb0[2], hb0[3]};
        *(u32x4*)&Bl[br][bk]     = (u32x4){lb0[0], lb0[1], lb0[2], lb0[3]};
        *(u32x4*)&Bh[br][bk + 8] = (u32x4){hb1[0], hb1[1], hb1[2], hb1[3]};
        *(u32x4*)&Bl[br][bk + 8] = (u32x4){lb1[0], lb1[1], lb1[2], lb1[3]};
        __syncthreads();

        short8 a_h = *(short8*)&Ah[fr][fo];
        short8 a_l = *(short8*)&Al[fr][fo];
#pragma unroll
        for (int f = 0; f < 8; ++f) {
            short8 b_h = *(short8*)&Bh[(f << 4) + (l & 15)][fo];
            short8 b_l = *(short8*)&Bl[(f << 4) + (l & 15)][fo];
            acc[f] = __builtin_amdgcn_mfma_f32_16x16x32_bf16(a_h, b_h, acc[f], 0, 0, 0);
            acc[f] = __builtin_amdgcn_mfma_f32_16x16x32_bf16(a_h, b_l, acc[f], 0, 0, 0);
            acc[f] = __builtin_amdgcn_mfma_f32_16x16x32_bf16(a_l, b_h, acc[f], 0, 0, 0);
        }
    }

    // C/D layout: col = lane&15, row = (lane>>4)*4 + reg
    const int rbase = row0 + (w << 4) + ((l >> 4) << 2);
    const int col = l & 15;

    // ---- bf16 fh store (RNE) ----
#pragma unroll
    for (int f = 0; f < 8; ++f)
#pragma unroll
        for (int r = 0; r < 4; ++r) {
            int gr = rbase + r;
            if (gr < N_NODES) {
                unsigned u = __float_as_uint(acc[f][r]);
                u += 0x7fffu + ((u >> 16) & 1u);
                fhb[(size_t)gr * HD + (f << 4) + col] = (unsigned short)(u >> 16);
            }
        }

    // ---- fused el/er: per-row per-head dot with attn vectors, 16-lane reduce ----
    float pl[4][4], pr[4][4];
#pragma unroll
    for (int r = 0; r < 4; ++r)
#pragma unroll
        for (int h = 0; h < 4; ++h) { pl[r][h] = 0.f; pr[r][h] = 0.f; }
#pragma unroll
    for (int f = 0; f < 8; ++f) {
        int c = (f << 4) + col;
        float alc = gal[c], arc = gar[c];
        int hh = f >> 1;
#pragma unroll
        for (int r = 0; r < 4; ++r) {
            pl[r][hh] += acc[f][r] * alc;
            pr[r][hh] += acc[f][r] * arc;
        }
    }
#pragma unroll
    for (int off = 8; off >= 1; off >>= 1)
#pragma unroll
        for (int r = 0; r < 4; ++r)
#pragma unroll
            for (int h = 0; h < 4; ++h) {
                pl[r][h] += __shfl_xor(pl[r][h], off, 16);
                pr[r][h] += __shfl_xor(pr[r][h], off, 16);
            }
    if (col == 0) {
#pragma unroll
        for (int r = 0; r < 4; ++r) {
            int gr = rbase + r;
            if (gr < N_NODES) {
#pragma unroll
                for (int h = 0; h < 4; ++h) {
                    el[gr * NH + h] = pl[r][h];
                    er[gr * NH + h] = pr[r][h];
                }
            }
        }
    }
}

// ---------------- fused per-node online softmax + bf16 PV + bias ----------------
// 32-lane group per node; lanes split: (lane&15)=8-channel group, (lane>>4)=edge of pair
#define NPB 8
__launch_bounds__(256)
__global__ void k_node(const int* __restrict__ row_ptr, const int* __restrict__ sorted_src,
                       const float4* __restrict__ el4, const float4* __restrict__ er4,
                       const unsigned short* __restrict__ fhb,
                       const float4* __restrict__ bias4, float4* __restrict__ out4) {
    __shared__ float lp[NPB][32 * 5];   // stride-5: conflict-free
    __shared__ int   lsrc[NPB][32];
    const int tid = threadIdx.x;
    const int g = tid >> 5;
    const int lane = tid & 31;
    const int n = blockIdx.x * NPB + g;
    if (n >= N_NODES) return;
    const int start = row_ptr[n], end = row_ptr[n + 1];
    const int half = lane >> 4;          // which edge of the pair
    const int cg   = lane & 15;          // channel octet: channels cg*8 .. cg*8+7
    const int h2   = cg >> 2;            // head of those channels

    const float4 r4 = er4[n];
    float4 m = make_float4(-INFINITY, -INFINITY, -INFINITY, -INFINITY);
    float4 s = make_float4(0.f, 0.f, 0.f, 0.f);
    float acc[8];
#pragma unroll
    for (int k = 0; k < 8; ++k) acc[k] = 0.f;

    for (int chunk = start; chunk < end; chunk += 32) {
        const int e = chunk + lane;
        float4 sc = make_float4(-INFINITY, -INFINITY, -INFINITY, -INFINITY);
        int sidx = 0;
        if (e < end) {
            sidx = sorted_src[e];
            float4 l4 = el4[sidx];
            sc.x = lrelu(l4.x + r4.x);
            sc.y = lrelu(l4.y + r4.y);
            sc.z = lrelu(l4.z + r4.z);
            sc.w = lrelu(l4.w + r4.w);
        }
        float4 cm = sc;
#pragma unroll
        for (int off = 16; off >= 1; off >>= 1) {
            cm.x = fmaxf(cm.x, __shfl_xor(cm.x, off, 32));
            cm.y = fmaxf(cm.y, __shfl_xor(cm.y, off, 32));
            cm.z = fmaxf(cm.z, __shfl_xor(cm.z, off, 32));
            cm.w = fmaxf(cm.w, __shfl_xor(cm.w, off, 32));
        }
        float4 mn;
        mn.x = fmaxf(m.x, cm.x); mn.y = fmaxf(m.y, cm.y);
        mn.z = fmaxf(m.z, cm.z); mn.w = fmaxf(m.w, cm.w);
        float4 scale;
        scale.x = expf(m.x - mn.x); scale.y = expf(m.y - mn.y);
        scale.z = expf(m.z - mn.z); scale.w = expf(m.w - mn.w);
        m = mn;
        float4 p;
        p.x = expf(sc.x - mn.x); p.y = expf(sc.y - mn.y);
        p.z = expf(sc.z - mn.z); p.w = expf(sc.w - mn.w);   // invalid lanes -> 0
        float4 ps = p;
#pragma unroll
        for (int off = 16; off >= 1; off >>= 1) {
            ps.x += __shfl_xor(ps.x, off, 32);
            ps.y += __shfl_xor(ps.y, off, 32);
            ps.z += __shfl_xor(ps.z, off, 32);
            ps.w += __shfl_xor(ps.w, off, 32);
        }
        s.x = s.x * scale.x + ps.x;
        s.y = s.y * scale.y + ps.y;
        s.z = s.z * scale.z + ps.z;
        s.w = s.w * scale.w + ps.w;
        float sh = h2 == 0 ? scale.x : h2 == 1 ? scale.y : h2 == 2 ? scale.z : scale.w;
#pragma unroll
        for (int k = 0; k < 8; ++k) acc[k] *= sh;

        lp[g][lane * 5 + 0] = p.x;
        lp[g][lane * 5 + 1] = p.y;
        lp[g][lane * 5 + 2] = p.z;
        lp[g][lane * 5 + 3] = p.w;
        lsrc[g][lane] = sidx;
        // same 32-lane group (one wave) wrote these; lockstep -> no barrier
        const int cnt = min(32, end - chunk);
        for (int j = 0; j < cnt; j += 2) {
            const int jj = j + half;
            const bool valid = jj < cnt;
            const int jx = valid ? jj : 0;
            float pj = lp[g][jx * 5 + h2];
            if (!valid) pj = 0.f;
            const int s2 = lsrc[g][jx];
            u32x4 raw = *(const u32x4*)(fhb + (size_t)s2 * HD + cg * 8);
#pragma unroll
            for (int t = 0; t < 4; ++t) {
                float lo = __uint_as_float(raw[t] << 16);
                float hi = __uint_as_float(raw[t] & 0xffff0000u);
                acc[2 * t]     += lo * pj;
                acc[2 * t + 1] += hi * pj;
            }
        }
    }
    // merge the two edge-halves
#pragma unroll
    for (int k = 0; k < 8; ++k) acc[k] += __shfl_xor(acc[k], 16, 32);

    float den = h2 == 0 ? s.x : h2 == 1 ? s.y : h2 == 2 ? s.z : s.w;
    float inv = den > 0.f ? 1.f / den : 0.f;
    if (half == 0) {
        float4 b0 = bias4[cg * 2 + 0];
        float4 b1 = bias4[cg * 2 + 1];
        float4 o0, o1;
        o0.x = acc[0] * inv + b0.x; o0.y = acc[1] * inv + b0.y;
        o0.z = acc[2] * inv + b0.z; o0.w = acc[3] * inv + b0.w;
        o1.x = acc[4] * inv + b1.x; o1.y = acc[5] * inv + b1.y;
        o1.z = acc[6] * inv + b1.z; o1.w = acc[7] * inv + b1.w;
        out4[(size_t)n * 32 + cg * 2 + 0] = o0;
        out4[(size_t)n * 32 + cg * 2 + 1] = o1;
    }
}

extern "C" void kernel_launch(void* const* d_in, const int* in_sizes, int n_in,
                              void* d_out, int out_size, void* d_ws, size_t ws_size,
                              hipStream_t stream) {
    const float* feat   = (const float*)d_in[0];
    const int*   src    = (const int*)d_in[1];
    const int*   dst    = (const int*)d_in[2];
    const float* W      = (const float*)d_in[3];
    const float* attn_l = (const float*)d_in[4];
    const float* attn_r = (const float*)d_in[5];
    const float* bias   = (const float*)d_in[6];
    float* out = (float*)d_out;

    char* ws = (char*)d_ws;
    size_t off = 0;
    auto take = [&](size_t bytes) {
        char* p = ws + off;
        off = (off + bytes + 255) & ~(size_t)255;
        return p;
    };
    unsigned short* fhb = (unsigned short*)take((size_t)N_NODES * HD * 2);  // 12.8 MB bf16
    int*   sorted_src   = (int*)take((size_t)N_EDGES * 4);                  // 3.2 MB
    float* el           = (float*)take((size_t)N_NODES * NH * 4);
    float* er           = (float*)take((size_t)N_NODES * NH * 4);
    int*   row_ptr      = (int*)take((size_t)(N_NODES + 1) * 4);
    int*   deg          = (int*)take((size_t)N_NODES * 4);
    int*   cursor       = (int*)take((size_t)N_NODES * 4);
    int*   bsum         = (int*)take((size_t)NB1 * 4);
    int*   boff         = (int*)take((size_t)NB1 * 4);
    (void)ws_size; (void)in_sizes; (void)n_in; (void)out_size;

    k_init<<<(N_NODES + 255) / 256, 256, 0, stream>>>(deg, cursor);
    k_hist<<<(N_EDGES + 255) / 256, 256, 0, stream>>>(dst, deg);
    k_scan1<<<NB1, SCAN_B, 0, stream>>>(deg, row_ptr, bsum);
    k_scan2<<<1, SCAN_B, 0, stream>>>(bsum, boff);
    k_scan3<<<NB1, SCAN_B, 0, stream>>>(row_ptr, boff);
    k_scatter<<<(N_EDGES + 255) / 256, 256, 0, stream>>>(src, dst, row_ptr, cursor, sorted_src);
    k_gemm<<<(N_NODES + BM - 1) / BM, 256, 0, stream>>>(feat, W, attn_l, attn_r, fhb, el, er);
    k_node<<<(N_NODES + NPB - 1) / NPB, 256, 0, stream>>>(
        row_ptr, sorted_src, (const float4*)el, (const float4*)er,
        fhb, (const float4*)bias, (float4*)out);
}

// Round 14
// 227.310 us; speedup vs baseline: 3.6312x; 1.0821x over previous
//
#include <hip/hip_runtime.h>
#include <math.h>

#define N_NODES 50000
#define N_EDGES 800000
#define IN_F    256
#define HD      128   // H*D
#define NH      4
#define NEG     0.2f

#define SCAN_B  256
#define NB1     ((N_NODES + SCAN_B - 1) / SCAN_B)   // 196

typedef __attribute__((ext_vector_type(8))) short short8;   // 8 x bf16 (guide-verified frag type)
typedef __attribute__((ext_vector_type(4))) float f32x4;
typedef __attribute__((ext_vector_type(4))) unsigned int u32x4;

__device__ __forceinline__ float lrelu(float x) { return x > 0.f ? x : NEG * x; }

// ---------------- init: zero deg ----------------
__global__ void k_init(int* __restrict__ deg) {
    int i = blockIdx.x * blockDim.x + threadIdx.x;
    if (i < N_NODES) deg[i] = 0;
}

// ---------------- degree histogram + per-edge rank (kills scatter atomics) ----------------
__global__ void k_hist(const int* __restrict__ dst, int* __restrict__ deg,
                       int* __restrict__ rank) {
    int e = blockIdx.x * blockDim.x + threadIdx.x;
    if (e < N_EDGES) rank[e] = atomicAdd(&deg[dst[e]], 1);
}

// ---------------- scan (3-kernel exclusive scan -> row_ptr) ----------------
__global__ void k_scan1(const int* __restrict__ deg, int* __restrict__ row_ptr,
                        int* __restrict__ bsum) {
    __shared__ int sm[SCAN_B];
    const int tid = threadIdx.x;
    const int t = blockIdx.x * SCAN_B + tid;
    int x = (t < N_NODES) ? deg[t] : 0;
    sm[tid] = x;
    __syncthreads();
#pragma unroll
    for (int off = 1; off < SCAN_B; off <<= 1) {
        int v = (tid >= off) ? sm[tid - off] : 0;
        __syncthreads();
        sm[tid] += v;
        __syncthreads();
    }
    if (t < N_NODES) row_ptr[t + 1] = sm[tid];
    if (tid == SCAN_B - 1) bsum[blockIdx.x] = sm[tid];
}

__global__ void k_scan2(const int* __restrict__ bsum, int* __restrict__ boff) {
    __shared__ int sm[SCAN_B];
    const int tid = threadIdx.x;
    int x = (tid < NB1) ? bsum[tid] : 0;
    sm[tid] = x;
    __syncthreads();
#pragma unroll
    for (int off = 1; off < SCAN_B; off <<= 1) {
        int v = (tid >= off) ? sm[tid - off] : 0;
        __syncthreads();
        sm[tid] += v;
        __syncthreads();
    }
    if (tid < NB1) boff[tid] = sm[tid] - x;
}

__global__ void k_scan3(int* __restrict__ row_ptr, const int* __restrict__ boff) {
    const int t = blockIdx.x * SCAN_B + threadIdx.x;
    if (t == 0) row_ptr[0] = 0;
    if (t < N_NODES) row_ptr[t + 1] += boff[blockIdx.x];
}

// ---------------- scatter: atomic-free (slot = row_ptr[d] + rank[e]) ----------------
__global__ void k_scatter(const int* __restrict__ src, const int* __restrict__ dst,
                          const int* __restrict__ row_ptr, const int* __restrict__ rank,
                          int* __restrict__ sorted_src) {
    int e = blockIdx.x * blockDim.x + threadIdx.x;
    if (e >= N_EDGES) return;
    int slot = row_ptr[dst[e]] + rank[e];
    __builtin_nontemporal_store(src[e], &sorted_src[slot]);
}

// ---------------- split-bf16 MFMA GEMM + fused el/er epilogue ----------------
// fh stored as bf16 [N][128]; el/er computed from fp32 accumulators in-block.
#define BM 64
#define KP 40   // padded k-stride in bf16 elems

__device__ __forceinline__ void split8(const float* __restrict__ p,
                                       unsigned* __restrict__ hu, unsigned* __restrict__ lu) {
    float v[8];
    *(float4*)(v)     = *(const float4*)(p);
    *(float4*)(v + 4) = *(const float4*)(p + 4);
#pragma unroll
    for (int j = 0; j < 4; ++j) {
        float a = v[2 * j], b = v[2 * j + 1];
        unsigned ha = __float_as_uint(a) >> 16;
        unsigned hb = __float_as_uint(b) >> 16;
        float ra = a - __uint_as_float(ha << 16);
        float rb = b - __uint_as_float(hb << 16);
        unsigned la = __float_as_uint(ra) >> 16;
        unsigned lb = __float_as_uint(rb) >> 16;
        hu[j] = ha | (hb << 16);
        lu[j] = la | (lb << 16);
    }
}

__launch_bounds__(256)
__global__ void k_gemm(const float* __restrict__ feat, const float* __restrict__ W,
                       const float* __restrict__ gal, const float* __restrict__ gar,
                       unsigned short* __restrict__ fhb,
                       float* __restrict__ el, float* __restrict__ er) {
    __shared__ unsigned short Ah[BM][KP], Al[BM][KP];
    __shared__ unsigned short Bh[HD][KP], Bl[HD][KP];
    const int tid = threadIdx.x;
    const int w = tid >> 6;
    const int l = tid & 63;
    const int row0 = blockIdx.x * BM;

    f32x4 acc[8];
#pragma unroll
    for (int f = 0; f < 8; ++f) acc[f] = (f32x4)(0.f);

    const int ar = tid >> 2;
    const int ak = (tid & 3) << 3;
    const int br = tid >> 1;
    const int bk = (tid & 1) << 4;
    int agr = row0 + ar; if (agr >= N_NODES) agr = N_NODES - 1;  // clamp; stores guarded
    const float* aptr = &feat[(size_t)agr * IN_F + ak];
    const float* bptr = &W[(size_t)br * IN_F + bk];

    const int fr = (w << 4) + (l & 15);
    const int fo = (l >> 4) << 3;

    for (int k0 = 0; k0 < IN_F; k0 += 32) {
        unsigned hua[4], lua[4], hb0[4], lb0[4], hb1[4], lb1[4];
        split8(aptr + k0, hua, lua);
        split8(bptr + k0, hb0, lb0);
        split8(bptr + k0 + 8, hb1, lb1);
        __syncthreads();
        *(u32x4*)&Ah[ar][ak]     = (u32x4){hua[0], hua[1], hua[2], hua[3]};
        *(u32x4*)&Al[ar][ak]     = (u32x4){lua[0], lua[1], lua[2], lua[3]};
        *(u32x4*)&Bh[br][bk]     = (u32x4){hb0[0], hb0[1], hb0[2], hb0[3]};
        *(u32x4*)&Bl[br][bk]     = (u32x4){lb0[0], lb0[1], lb0[2], lb0[3]};
        *(u32x4*)&Bh[br][bk + 8] = (u32x4){hb1[0], hb1[1], hb1[2], hb1[3]};
        *(u32x4*)&Bl[br][bk + 8] = (u32x4){lb1[0], lb1[1], lb1[2], lb1[3]};
        __syncthreads();

        short8 a_h = *(short8*)&Ah[fr][fo];
        short8 a_l = *(short8*)&Al[fr][fo];
#pragma unroll
        for (int f = 0; f < 8; ++f) {
            short8 b_h = *(short8*)&Bh[(f << 4) + (l & 15)][fo];
            short8 b_l = *(short8*)&Bl[(f << 4) + (l & 15)][fo];
            acc[f] = __builtin_amdgcn_mfma_f32_16x16x32_bf16(a_h, b_h, acc[f], 0, 0, 0);
            acc[f] = __builtin_amdgcn_mfma_f32_16x16x32_bf16(a_h, b_l, acc[f], 0, 0, 0);
            acc[f] = __builtin_amdgcn_mfma_f32_16x16x32_bf16(a_l, b_h, acc[f], 0, 0, 0);
        }
    }

    // C/D layout: col = lane&15, row = (lane>>4)*4 + reg
    const int rbase = row0 + (w << 4) + ((l >> 4) << 2);
    const int col = l & 15;

    // ---- bf16 fh store (RNE) ----
#pragma unroll
    for (int f = 0; f < 8; ++f)
#pragma unroll
        for (int r = 0; r < 4; ++r) {
            int gr = rbase + r;
            if (gr < N_NODES) {
                unsigned u = __float_as_uint(acc[f][r]);
                u += 0x7fffu + ((u >> 16) & 1u);
                fhb[(size_t)gr * HD + (f << 4) + col] = (unsigned short)(u >> 16);
            }
        }

    // ---- fused el/er: per-row per-head dot with attn vectors, 16-lane reduce ----
    float pl[4][4], pr[4][4];
#pragma unroll
    for (int r = 0; r < 4; ++r)
#pragma unroll
        for (int h = 0; h < 4; ++h) { pl[r][h] = 0.f; pr[r][h] = 0.f; }
#pragma unroll
    for (int f = 0; f < 8; ++f) {
        int c = (f << 4) + col;
        float alc = gal[c], arc = gar[c];
        int hh = f >> 1;
#pragma unroll
        for (int r = 0; r < 4; ++r) {
            pl[r][hh] += acc[f][r] * alc;
            pr[r][hh] += acc[f][r] * arc;
        }
    }
#pragma unroll
    for (int off = 8; off >= 1; off >>= 1)
#pragma unroll
        for (int r = 0; r < 4; ++r)
#pragma unroll
            for (int h = 0; h < 4; ++h) {
                pl[r][h] += __shfl_xor(pl[r][h], off, 16);
                pr[r][h] += __shfl_xor(pr[r][h], off, 16);
            }
    if (col == 0) {
#pragma unroll
        for (int r = 0; r < 4; ++r) {
            int gr = rbase + r;
            if (gr < N_NODES) {
#pragma unroll
                for (int h = 0; h < 4; ++h) {
                    el[gr * NH + h] = pl[r][h];
                    er[gr * NH + h] = pr[r][h];
                }
            }
        }
    }
}

// ---------------- fused per-node online softmax + bf16 PV + bias ----------------
// 32-lane group per node; lanes split: (lane&15)=8-channel group, (lane>>4)=edge of pair
#define NPB 8
__launch_bounds__(256)
__global__ void k_node(const int* __restrict__ row_ptr, const int* __restrict__ sorted_src,
                       const float4* __restrict__ el4, const float4* __restrict__ er4,
                       const unsigned short* __restrict__ fhb,
                       const float4* __restrict__ bias4, float4* __restrict__ out4) {
    __shared__ float lp[NPB][32 * 5];   // stride-5: conflict-free
    __shared__ int   lsrc[NPB][32];
    const int tid = threadIdx.x;
    const int g = tid >> 5;
    const int lane = tid & 31;
    const int n = blockIdx.x * NPB + g;
    if (n >= N_NODES) return;
    const int start = row_ptr[n], end = row_ptr[n + 1];
    const int half = lane >> 4;          // which edge of the pair
    const int cg   = lane & 15;          // channel octet: channels cg*8 .. cg*8+7
    const int h2   = cg >> 2;            // head of those channels

    const float4 r4 = er4[n];
    float4 m = make_float4(-INFINITY, -INFINITY, -INFINITY, -INFINITY);
    float4 s = make_float4(0.f, 0.f, 0.f, 0.f);
    float acc[8];
#pragma unroll
    for (int k = 0; k < 8; ++k) acc[k] = 0.f;

    for (int chunk = start; chunk < end; chunk += 32) {
        const int e = chunk + lane;
        float4 sc = make_float4(-INFINITY, -INFINITY, -INFINITY, -INFINITY);
        int sidx = 0;
        if (e < end) {
            sidx = sorted_src[e];
            float4 l4 = el4[sidx];
            sc.x = lrelu(l4.x + r4.x);
            sc.y = lrelu(l4.y + r4.y);
            sc.z = lrelu(l4.z + r4.z);
            sc.w = lrelu(l4.w + r4.w);
        }
        float4 cm = sc;
#pragma unroll
        for (int off = 16; off >= 1; off >>= 1) {
            cm.x = fmaxf(cm.x, __shfl_xor(cm.x, off, 32));
            cm.y = fmaxf(cm.y, __shfl_xor(cm.y, off, 32));
            cm.z = fmaxf(cm.z, __shfl_xor(cm.z, off, 32));
            cm.w = fmaxf(cm.w, __shfl_xor(cm.w, off, 32));
        }
        float4 mn;
        mn.x = fmaxf(m.x, cm.x); mn.y = fmaxf(m.y, cm.y);
        mn.z = fmaxf(m.z, cm.z); mn.w = fmaxf(m.w, cm.w);
        float4 scale;
        scale.x = expf(m.x - mn.x); scale.y = expf(m.y - mn.y);
        scale.z = expf(m.z - mn.z); scale.w = expf(m.w - mn.w);
        m = mn;
        float4 p;
        p.x = expf(sc.x - mn.x); p.y = expf(sc.y - mn.y);
        p.z = expf(sc.z - mn.z); p.w = expf(sc.w - mn.w);   // invalid lanes -> 0
        float4 ps = p;
#pragma unroll
        for (int off = 16; off >= 1; off >>= 1) {
            ps.x += __shfl_xor(ps.x, off, 32);
            ps.y += __shfl_xor(ps.y, off, 32);
            ps.z += __shfl_xor(ps.z, off, 32);
            ps.w += __shfl_xor(ps.w, off, 32);
        }
        s.x = s.x * scale.x + ps.x;
        s.y = s.y * scale.y + ps.y;
        s.z = s.z * scale.z + ps.z;
        s.w = s.w * scale.w + ps.w;
        float sh = h2 == 0 ? scale.x : h2 == 1 ? scale.y : h2 == 2 ? scale.z : scale.w;
#pragma unroll
        for (int k = 0; k < 8; ++k) acc[k] *= sh;

        lp[g][lane * 5 + 0] = p.x;
        lp[g][lane * 5 + 1] = p.y;
        lp[g][lane * 5 + 2] = p.z;
        lp[g][lane * 5 + 3] = p.w;
        lsrc[g][lane] = sidx;
        // same 32-lane group (one wave) wrote these; lockstep -> no barrier
        const int cnt = min(32, end - chunk);
        for (int j = 0; j < cnt; j += 2) {
            const int jj = j + half;
            const bool valid = jj < cnt;
            const int jx = valid ? jj : 0;
            float pj = lp[g][jx * 5 + h2];
            if (!valid) pj = 0.f;
            const int s2 = lsrc[g][jx];
            u32x4 raw = *(const u32x4*)(fhb + (size_t)s2 * HD + cg * 8);
#pragma unroll
            for (int t = 0; t < 4; ++t) {
                float lo = __uint_as_float(raw[t] << 16);
                float hi = __uint_as_float(raw[t] & 0xffff0000u);
                acc[2 * t]     += lo * pj;
                acc[2 * t + 1] += hi * pj;
            }
        }
    }
    // merge the two edge-halves
#pragma unroll
    for (int k = 0; k < 8; ++k) acc[k] += __shfl_xor(acc[k], 16, 32);

    float den = h2 == 0 ? s.x : h2 == 1 ? s.y : h2 == 2 ? s.z : s.w;
    float inv = den > 0.f ? 1.f / den : 0.f;
    if (half == 0) {
        float4 b0 = bias4[cg * 2 + 0];
        float4 b1 = bias4[cg * 2 + 1];
        float4 o0, o1;
        o0.x = acc[0] * inv + b0.x; o0.y = acc[1] * inv + b0.y;
        o0.z = acc[2] * inv + b0.z; o0.w = acc[3] * inv + b0.w;
        o1.x = acc[4] * inv + b1.x; o1.y = acc[5] * inv + b1.y;
        o1.z = acc[6] * inv + b1.z; o1.w = acc[7] * inv + b1.w;
        out4[(size_t)n * 32 + cg * 2 + 0] = o0;
        out4[(size_t)n * 32 + cg * 2 + 1] = o1;
    }
}

extern "C" void kernel_launch(void* const* d_in, const int* in_sizes, int n_in,
                              void* d_out, int out_size, void* d_ws, size_t ws_size,
                              hipStream_t stream) {
    const float* feat   = (const float*)d_in[0];
    const int*   src    = (const int*)d_in[1];
    const int*   dst    = (const int*)d_in[2];
    const float* W      = (const float*)d_in[3];
    const float* attn_l = (const float*)d_in[4];
    const float* attn_r = (const float*)d_in[5];
    const float* bias   = (const float*)d_in[6];
    float* out = (float*)d_out;

    char* ws = (char*)d_ws;
    size_t off = 0;
    auto take = [&](size_t bytes) {
        char* p = ws + off;
        off = (off + bytes + 255) & ~(size_t)255;
        return p;
    };
    unsigned short* fhb = (unsigned short*)take((size_t)N_NODES * HD * 2);  // 12.8 MB bf16
    int*   sorted_src   = (int*)take((size_t)N_EDGES * 4);                  // 3.2 MB
    int*   rank         = (int*)take((size_t)N_EDGES * 4);                  // 3.2 MB
    float* el           = (float*)take((size_t)N_NODES * NH * 4);
    float* er           = (float*)take((size_t)N_NODES * NH * 4);
    int*   row_ptr      = (int*)take((size_t)(N_NODES + 1) * 4);
    int*   deg          = (int*)take((size_t)N_NODES * 4);
    int*   bsum         = (int*)take((size_t)NB1 * 4);
    int*   boff         = (int*)take((size_t)NB1 * 4);
    (void)ws_size; (void)in_sizes; (void)n_in; (void)out_size;

    k_init<<<(N_NODES + 255) / 256, 256, 0, stream>>>(deg);
    k_hist<<<(N_EDGES + 255) / 256, 256, 0, stream>>>(dst, deg, rank);
    k_scan1<<<NB1, SCAN_B, 0, stream>>>(deg, row_ptr, bsum);
    k_scan2<<<1, SCAN_B, 0, stream>>>(bsum, boff);
    k_scan3<<<NB1, SCAN_B, 0, stream>>>(row_ptr, boff);
    k_scatter<<<(N_EDGES + 255) / 256, 256, 0, stream>>>(src, dst, row_ptr, rank, sorted_src);
    k_gemm<<<(N_NODES + BM - 1) / BM, 256, 0, stream>>>(feat, W, attn_l, attn_r, fhb, el, er);
    k_node<<<(N_NODES + NPB - 1) / NPB, 256, 0, stream>>>(
        row_ptr, sorted_src, (const float4*)el, (const float4*)er,
        fhb, (const float4*)bias, (float4*)out);
}